// Round 12
// baseline (533.121 us; speedup 1.0000x reference)
//
#include <hip/hip_runtime.h>

#define HID 10
#define TT  2048
#define BB  4096

typedef float f2 __attribute__((ext_vector_type(2)));

static __device__ __forceinline__ f2 pkmul(f2 a, f2 b) {
    f2 d; asm("v_pk_mul_f32 %0, %1, %2" : "=v"(d) : "v"(a), "v"(b)); return d;
}
static __device__ __forceinline__ f2 pkfma(f2 a, f2 b, f2 c) {
    f2 d; asm("v_pk_fma_f32 %0, %1, %2, %3" : "=v"(d) : "v"(a), "v"(b), "v"(c)); return d;
}

__device__ __forceinline__ float fast_tanh(float x) {
    // tanh(x) = 1 - 2/(exp2(x*2*log2e) + 1); saturates correctly at +-inf
    float e = exp2f(x * 2.885390081777926814f);
    float r = __builtin_amdgcn_rcpf(e + 1.0f);
    return fmaf(-2.0f, r, 1.0f);
}

__device__ __forceinline__ float bperm(int idx, float v) {
    return __int_as_float(__builtin_amdgcn_ds_bpermute(idx, __float_as_int(v)));
}

// R11 3-wave specialization with ds_bpermute broadcasts on the chains:
//   wave A  : h0 recurrence. Broadcast of h0(t-1) = 10 independent bpermute
//             pulls (no write->read LDS round-trip on the chain). Publishes
//             h0(t) to a 16-slot ring (off-chain) for B1.
//   wave B1 : u(t) = Wih1.h0(t)+b1, feed-forward over lag-1-epoch ring, pk
//             math; writes scalar u-ring. Lane10: u = b_out (Wout rider bias).
//   wave B2 : h1 recurrence: s1 = u + Whh1.h1(t-1); h1 broadcast also via
//             bpermute (h1 LDS buffer eliminated). Lane10 rides Wout -> s1 =
//             out(t-1); stored with lag-1 quad carry.
// Epochs of 8 steps, one __syncthreads per epoch (258 barriers vs R11's 514).
__global__ void __launch_bounds__(192) rnn_kernel(
    const float* __restrict__ x,    const float* __restrict__ hs,
    const float* __restrict__ Wih0, const float* __restrict__ Whh0,
    const float* __restrict__ bih0, const float* __restrict__ bhh0,
    const float* __restrict__ Wih1, const float* __restrict__ Whh1,
    const float* __restrict__ bih1, const float* __restrict__ bhh1,
    const float* __restrict__ Wout, const float* __restrict__ boutp,
    float* __restrict__ out)
{
    const int tid   = threadIdx.x;
    const int role  = tid >> 6;          // 0=A, 1=B1, 2=B2
    const int lane  = tid & 15;          // hidden unit slot
    const int grp   = (tid >> 4) & 3;    // row within block
    const int row   = blockIdx.x * 4 + grp;
    const bool act  = (lane < HID);
    const bool olane = (lane == HID);

    // per row (stride 528 floats == 16 mod 32 banks -> groups alternate bank
    // phase 0/16, <=2-way aliasing = free): h0 ring [16][16] | u ring [16][16]
    __shared__ float lds[4 * 528];
    float* h0r = &lds[grp * 528];
    float* ur  = h0r + 256;

    // bpermute byte-indices for pulling units 0..9 of this 16-lane group
    int bpidx[HID];
    #pragma unroll
    for (int j = 0; j < HID; ++j) bpidx[j] = ((tid & 48) + j) * 4;

    const float* xrow = x   + (size_t)row * TT;
    float*       orow = out + (size_t)row * TT;

    // ---- role state ----
    float w0[HID], wih0i = 0.f, b0c = 0.f;   // A: scalar Whh0 row
    f2 w1p[5]; float ub = 0.f;               // B1
    float w2[HID];                            // B2: scalar Whh1 row / Wout
    float hown = 0.f;                         // A: h0 own-unit | B2: h1 own-unit
    float4 xa = make_float4(0,0,0,0), xb = make_float4(0,0,0,0);
    float P1 = 0.f, P2 = 0.f, P3 = 0.f;       // B2 out-store carry
    float obias = 0.f;                        // B2: lane10 epilogue bias

    if (role == 0) {
        #pragma unroll
        for (int j = 0; j < HID; ++j) w0[j] = act ? Whh0[lane*HID + j] : 0.f;
        wih0i = act ? Wih0[lane] : 0.f;
        b0c   = act ? (bih0[lane] + bhh0[lane]) : 0.f;
        hown  = act ? hs[row*HID + lane] : 0.f;
        xa = *(const float4*)(xrow);
        xb = *(const float4*)(xrow + 4);
    } else if (role == 1) {
        #pragma unroll
        for (int j = 0; j < 5; ++j)
            w1p[j] = act ? f2{Wih1[lane*HID + 2*j], Wih1[lane*HID + 2*j+1]}
                         : f2{0.f, 0.f};
        ub = act ? (bih1[lane] + bhh1[lane]) : (olane ? boutp[0] : 0.f);
    } else {
        #pragma unroll
        for (int j = 0; j < HID; ++j)
            w2[j] = act ? Whh1[lane*HID + j] : (olane ? Wout[j] : 0.f);
        hown  = act ? hs[BB*HID + row*HID + lane] : 0.f;
        obias = olane ? boutp[0] : 0.f;
    }

    const int M = TT / 8;   // 256 epochs of 8 steps
    for (int m = 0; m <= M + 1; ++m) {
        if (role == 0) {
            if (m < M) {
                const int mn = (m + 1 < M) ? m + 1 : M - 1;
                const float4 xn0 = *(const float4*)(xrow + 8 * mn);
                const float4 xn1 = *(const float4*)(xrow + 8 * mn + 4);
                const float xs[8] = {xa.x, xa.y, xa.z, xa.w,
                                     xb.x, xb.y, xb.z, xb.w};
                #pragma unroll
                for (int k = 0; k < 8; ++k) {
                    // broadcast h0(t-1): 10 independent crossbar pulls
                    float r0 = bperm(bpidx[0], hown);
                    float r1 = bperm(bpidx[1], hown);
                    float r2 = bperm(bpidx[2], hown);
                    float r3 = bperm(bpidx[3], hown);
                    float r4 = bperm(bpidx[4], hown);
                    float r5 = bperm(bpidx[5], hown);
                    float r6 = bperm(bpidx[6], hown);
                    float r7 = bperm(bpidx[7], hown);
                    float r8 = bperm(bpidx[8], hown);
                    float r9 = bperm(bpidx[9], hown);
                    float a = fmaf(xs[k], wih0i, b0c), b = 0.f;  // off-chain join
                    a = fmaf(w0[0], r0, a); b = fmaf(w0[1], r1, b);
                    a = fmaf(w0[2], r2, a); b = fmaf(w0[3], r3, b);
                    a = fmaf(w0[4], r4, a); b = fmaf(w0[5], r5, b);
                    a = fmaf(w0[6], r6, a); b = fmaf(w0[7], r7, b);
                    a = fmaf(w0[8], r8, a); b = fmaf(w0[9], r9, b);
                    hown = fast_tanh(a + b);
                    h0r[((8*m + k) & 15) * 16 + lane] = hown;   // publish (off-chain)
                }
                xa = xn0; xb = xn1;
            }
        } else if (role == 1) {
            if (m >= 1 && m <= M) {
                const int tb = 8 * (m - 1);
                #pragma unroll
                for (int k = 0; k < 8; ++k) {
                    const float* rb = h0r + ((tb + k) & 15) * 16;
                    const f2 h0a = *(const f2*)(rb);
                    const f2 h0b = *(const f2*)(rb + 2);
                    const f2 h0c = *(const f2*)(rb + 4);
                    const f2 h0d = *(const f2*)(rb + 6);
                    const f2 h0e = *(const f2*)(rb + 8);
                    f2 pc = pkmul(w1p[0], h0a);
                    pc = pkfma(w1p[1], h0b, pc);
                    pc = pkfma(w1p[2], h0c, pc);
                    pc = pkfma(w1p[3], h0d, pc);
                    pc = pkfma(w1p[4], h0e, pc);
                    ur[((tb + k) & 15) * 16 + lane] = (ub + pc.x) + pc.y;
                }
            }
        } else {
            if (m >= 2 && m <= M + 1) {
                const int tb = 8 * (m - 2);
                // u's from lag-1-epoch ring: 8 independent reads, latency
                // covered by the bperm/fmac work below
                float u[8];
                #pragma unroll
                for (int k = 0; k < 8; ++k)
                    u[k] = ur[((tb + k) & 15) * 16 + lane];
                float c[8];
                #pragma unroll
                for (int k = 0; k < 8; ++k) {
                    float q0 = bperm(bpidx[0], hown);
                    float q1 = bperm(bpidx[1], hown);
                    float q2 = bperm(bpidx[2], hown);
                    float q3 = bperm(bpidx[3], hown);
                    float q4 = bperm(bpidx[4], hown);
                    float q5 = bperm(bpidx[5], hown);
                    float q6 = bperm(bpidx[6], hown);
                    float q7 = bperm(bpidx[7], hown);
                    float q8 = bperm(bpidx[8], hown);
                    float q9 = bperm(bpidx[9], hown);
                    float a = u[k], b = 0.f;
                    a = fmaf(w2[0], q0, a); b = fmaf(w2[1], q1, b);
                    a = fmaf(w2[2], q2, a); b = fmaf(w2[3], q3, b);
                    a = fmaf(w2[4], q4, a); b = fmaf(w2[5], q5, b);
                    a = fmaf(w2[6], q6, a); b = fmaf(w2[7], q7, b);
                    a = fmaf(w2[8], q8, a); b = fmaf(w2[9], q9, b);
                    const float s1 = a + b;     // lane10: out(tb+k-1)
                    c[k] = s1;
                    hown = fast_tanh(s1);
                }
                // c[k] = out(tb+k-1): aligned quads with 1-step lag
                if (olane) {
                    if (m >= 3)
                        *(float4*)(orow + tb - 4) = make_float4(P1, P2, P3, c[0]);
                    *(float4*)(orow + tb) = make_float4(c[1], c[2], c[3], c[4]);
                }
                P1 = c[5]; P2 = c[6]; P3 = c[7];
            }
        }
        __syncthreads();
    }

    if (role == 2) {
        // epilogue: out(2047) = bout + Wout . h1(2047) via rider weights
        float q0 = bperm(bpidx[0], hown);
        float q1 = bperm(bpidx[1], hown);
        float q2 = bperm(bpidx[2], hown);
        float q3 = bperm(bpidx[3], hown);
        float q4 = bperm(bpidx[4], hown);
        float q5 = bperm(bpidx[5], hown);
        float q6 = bperm(bpidx[6], hown);
        float q7 = bperm(bpidx[7], hown);
        float q8 = bperm(bpidx[8], hown);
        float q9 = bperm(bpidx[9], hown);
        float a = obias, b = 0.f;
        a = fmaf(w2[0], q0, a); b = fmaf(w2[1], q1, b);
        a = fmaf(w2[2], q2, a); b = fmaf(w2[3], q3, b);
        a = fmaf(w2[4], q4, a); b = fmaf(w2[5], q5, b);
        a = fmaf(w2[6], q6, a); b = fmaf(w2[7], q7, b);
        a = fmaf(w2[8], q8, a); b = fmaf(w2[9], q9, b);
        if (olane)
            *(float4*)(orow + TT - 4) = make_float4(P1, P2, P3, a + b);
        if (act)
            out[(size_t)BB*TT + (size_t)BB*HID + (size_t)row*HID + lane] = hown;
    }
    if (role == 0 && act)
        out[(size_t)BB*TT + (size_t)row*HID + lane] = hown;
}

extern "C" void kernel_launch(void* const* d_in, const int* in_sizes, int n_in,
                              void* d_out, int out_size, void* d_ws, size_t ws_size,
                              hipStream_t stream) {
    const float* x    = (const float*)d_in[0];
    const float* hs   = (const float*)d_in[1];
    const float* Wih0 = (const float*)d_in[2];
    const float* Whh0 = (const float*)d_in[3];
    const float* bih0 = (const float*)d_in[4];
    const float* bhh0 = (const float*)d_in[5];
    const float* Wih1 = (const float*)d_in[6];
    const float* Whh1 = (const float*)d_in[7];
    const float* bih1 = (const float*)d_in[8];
    const float* bhh1 = (const float*)d_in[9];
    const float* Wout = (const float*)d_in[10];
    const float* bout = (const float*)d_in[11];
    float* out = (float*)d_out;

    dim3 grid(BB / 4), block(192);
    hipLaunchKernelGGL(rnn_kernel, grid, block, 0, stream,
        x, hs, Wih0, Whh0, bih0, bhh0, Wih1, Whh1, bih1, bhh1, Wout, bout, out);
}

// Round 14
// 443.245 us; speedup vs baseline: 1.2028x; 1.2028x over previous
//
#include <hip/hip_runtime.h>

#define HID 10
#define TT  2048
#define BB  4096

__device__ __forceinline__ float fast_tanh(float x) {
    // tanh(x) = 1 - 2/(exp2(x*2*log2e) + 1); saturates correctly at +-inf
    float e = exp2f(x * 2.885390081777926814f);
    float r = __builtin_amdgcn_rcpf(e + 1.0f);
    return fmaf(-2.0f, r, 1.0f);
}

// DPP row-rotate within 16-lane rows; direction handled by self-calibration.
template<int CTRL>
__device__ __forceinline__ int rori(int v) {
    return __builtin_amdgcn_update_dpp(0, v, CTRL, 0xF, 0xF, true);
}
template<int CTRL>
__device__ __forceinline__ float rorf(float v) {
    return __int_as_float(
        __builtin_amdgcn_update_dpp(0, __float_as_int(v), CTRL, 0xF, 0xF, true));
}

// FULL 16-slot broadcast of SRC (15 DPP movs + identity). R13's bug: a
// 10-rotation subset does NOT cover all units (lane 8 saw only {8,9,0,1}).
#define REROT16(rot, SRC)                                     \
    rot[0]  = (SRC);                                          \
    rot[1]  = rorf<0x121>(SRC); rot[2]  = rorf<0x122>(SRC);   \
    rot[3]  = rorf<0x123>(SRC); rot[4]  = rorf<0x124>(SRC);   \
    rot[5]  = rorf<0x125>(SRC); rot[6]  = rorf<0x126>(SRC);   \
    rot[7]  = rorf<0x127>(SRC); rot[8]  = rorf<0x128>(SRC);   \
    rot[9]  = rorf<0x129>(SRC); rot[10] = rorf<0x12A>(SRC);   \
    rot[11] = rorf<0x12B>(SRC); rot[12] = rorf<0x12C>(SRC);   \
    rot[13] = rorf<0x12D>(SRC); rot[14] = rorf<0x12E>(SRC);   \
    rot[15] = rorf<0x12F>(SRC);

// 16-term rotation dot: two chains, accumulates onto A0 (preloaded)
#define DOT16(W, R, A0, B0)                                    \
    A0 = fmaf(W[0],  R[0],  A0); B0 = fmaf(W[1],  R[1],  B0);  \
    A0 = fmaf(W[2],  R[2],  A0); B0 = fmaf(W[3],  R[3],  B0);  \
    A0 = fmaf(W[4],  R[4],  A0); B0 = fmaf(W[5],  R[5],  B0);  \
    A0 = fmaf(W[6],  R[6],  A0); B0 = fmaf(W[7],  R[7],  B0);  \
    A0 = fmaf(W[8],  R[8],  A0); B0 = fmaf(W[9],  R[9],  B0);  \
    A0 = fmaf(W[10], R[10], A0); B0 = fmaf(W[11], R[11], B0);  \
    A0 = fmaf(W[12], R[12], A0); B0 = fmaf(W[13], R[13], B0);  \
    A0 = fmaf(W[14], R[14], A0); B0 = fmaf(W[15], R[15], B0);

// 2-wave specialization, broadcasts in-register (DPP), DS = 2 b32/step:
//   wave A: h0 recurrence via DPP; also computes u(t) = Wih1.h0(t)+b1 from
//           the same rotation set and publishes ONE scalar to the u-ring.
//           Lane 10's u := b_out (rider feed), its Wih1 row := 0.
//   wave B: h1 recurrence via DPP; reads only scalar u (lag-1 epoch).
//           Lane 10 rides Wout on the Whh1 dot -> s1 = out(t-1); stored
//           with the proven 1-step-lag quad carry.
// R8/R11 were DS-pipe-throughput-bound (~11-13 DS insts/block-step); this
// kernel cuts DS to 2 (1 write by A + 1 read by B) per block-step.
__global__ void __launch_bounds__(128) rnn_kernel(
    const float* __restrict__ x,    const float* __restrict__ hs,
    const float* __restrict__ Wih0, const float* __restrict__ Whh0,
    const float* __restrict__ bih0, const float* __restrict__ bhh0,
    const float* __restrict__ Wih1, const float* __restrict__ Whh1,
    const float* __restrict__ bih1, const float* __restrict__ bhh1,
    const float* __restrict__ Wout, const float* __restrict__ boutp,
    float* __restrict__ out)
{
    const int tid   = threadIdx.x;
    const bool isA  = tid < 64;
    const int lane  = tid & 15;          // hidden unit slot
    const int grp   = (tid >> 4) & 3;    // row within block
    const int row   = blockIdx.x * 4 + grp;
    const bool act  = (lane < HID);
    const bool olane = (lane == HID);

    // u ring [16][16] per row; stride 272 == 16 mod 32 banks -> <=2-way (free)
    __shared__ float lds[4 * 272];
    float* ur = &lds[grp * 272];

    // self-calibrate: jj[r] = unit index delivered by ror_r (r = 0..15)
    int jj[16];
    jj[0]  = lane;
    jj[1]  = rori<0x121>(lane); jj[2]  = rori<0x122>(lane);
    jj[3]  = rori<0x123>(lane); jj[4]  = rori<0x124>(lane);
    jj[5]  = rori<0x125>(lane); jj[6]  = rori<0x126>(lane);
    jj[7]  = rori<0x127>(lane); jj[8]  = rori<0x128>(lane);
    jj[9]  = rori<0x129>(lane); jj[10] = rori<0x12A>(lane);
    jj[11] = rori<0x12B>(lane); jj[12] = rori<0x12C>(lane);
    jj[13] = rori<0x12D>(lane); jj[14] = rori<0x12E>(lane);
    jj[15] = rori<0x12F>(lane);

    const float* xrow = x   + (size_t)row * TT;
    float*       orow = out + (size_t)row * TT;

    // ---- role state ----
    float w0[16], w1[16], w2[16];   // A: Whh0,Wih1 | B: Whh1/Wout (rot-indexed)
    float wih0i = 0.f, b0c = 0.f, ub = 0.f, obias = 0.f;
    float rot[16];                   // broadcast of own-layer h(t-1)
    float hown = 0.f;
    float4 xa = make_float4(0,0,0,0), xb = make_float4(0,0,0,0);
    float P1 = 0.f, P2 = 0.f, P3 = 0.f;

    if (isA) {
        #pragma unroll
        for (int r = 0; r < 16; ++r) {
            const bool ok = act && (jj[r] < HID);
            w0[r] = ok ? Whh0[lane * HID + jj[r]] : 0.f;
            w1[r] = ok ? Wih1[lane * HID + jj[r]] : 0.f;
            w2[r] = 0.f;
        }
        wih0i = act ? Wih0[lane] : 0.f;
        b0c   = act ? (bih0[lane] + bhh0[lane]) : 0.f;
        ub    = act ? (bih1[lane] + bhh1[lane]) : (olane ? boutp[0] : 0.f);
        #pragma unroll
        for (int r = 0; r < 16; ++r)
            rot[r] = (jj[r] < HID) ? hs[row * HID + jj[r]] : 0.f;
        hown = act ? hs[row * HID + lane] : 0.f;
        xa = *(const float4*)(xrow);
        xb = *(const float4*)(xrow + 4);
    } else {
        #pragma unroll
        for (int r = 0; r < 16; ++r) {
            w2[r] = (jj[r] < HID)
                  ? (act ? Whh1[lane * HID + jj[r]]
                         : (olane ? Wout[jj[r]] : 0.f))
                  : 0.f;
            w0[r] = 0.f; w1[r] = 0.f;
        }
        obias = olane ? boutp[0] : 0.f;
        #pragma unroll
        for (int r = 0; r < 16; ++r)
            rot[r] = (jj[r] < HID) ? hs[BB*HID + row*HID + jj[r]] : 0.f;
        hown = act ? hs[BB*HID + row*HID + lane] : 0.f;
    }

    const int M = TT / 8;   // 256 epochs of 8 steps
    for (int m = 0; m <= M; ++m) {
        if (isA) {
            if (m < M) {
                const int mn = (m + 1 < M) ? m + 1 : M - 1;
                const float4 xn0 = *(const float4*)(xrow + 8 * mn);
                const float4 xn1 = *(const float4*)(xrow + 8 * mn + 4);
                const float xs[8] = {xa.x, xa.y, xa.z, xa.w,
                                     xb.x, xb.y, xb.z, xb.w};
                #pragma unroll
                for (int k = 0; k < 8; ++k) {
                    // h0(t) = tanh(x*wih0 + Whh0 . h0(t-1) + b0)
                    float a = fmaf(xs[k], wih0i, b0c), b = 0.f;
                    DOT16(w0, rot, a, b);
                    hown = fast_tanh(a + b);
                    REROT16(rot, hown);            // broadcast h0(t)
                    // u(t) = Wih1 . h0(t) + b1  (lane10: bout) -> publish
                    float ua = ub, vb = 0.f;
                    DOT16(w1, rot, ua, vb);
                    ur[((8 * m + k) & 15) * 16 + lane] = ua + vb;
                }
                xa = xn0; xb = xn1;
            }
        } else {
            if (m >= 1) {
                const int tb = 8 * (m - 1);
                float u[8];
                #pragma unroll
                for (int k = 0; k < 8; ++k)
                    u[k] = ur[((tb + k) & 15) * 16 + lane];
                float c[8];
                #pragma unroll
                for (int k = 0; k < 8; ++k) {
                    // s1(t) = u(t) + Whh1 . h1(t-1)   (rider: out(t-1))
                    float a = u[k], b = 0.f;
                    DOT16(w2, rot, a, b);
                    const float s1 = a + b;
                    c[k] = s1;
                    hown = fast_tanh(s1);
                    REROT16(rot, hown);            // broadcast h1(t)
                }
                // c[k] = out(tb+k-1): aligned quads, 1-step lag
                if (olane) {
                    if (m >= 2)
                        *(float4*)(orow + tb - 4) = make_float4(P1, P2, P3, c[0]);
                    *(float4*)(orow + tb) = make_float4(c[1], c[2], c[3], c[4]);
                }
                P1 = c[5]; P2 = c[6]; P3 = c[7];
            }
        }
        __syncthreads();
    }

    if (!isA) {
        // epilogue: out(2047) = bout + Wout . h1(2047) via rider weights
        float a = obias, b = 0.f;
        DOT16(w2, rot, a, b);
        if (olane)
            *(float4*)(orow + TT - 4) = make_float4(P1, P2, P3, a + b);
        if (act)
            out[(size_t)BB*TT + (size_t)BB*HID + (size_t)row*HID + lane] = hown;
    } else {
        if (act)
            out[(size_t)BB*TT + (size_t)row*HID + lane] = hown;
    }
}

extern "C" void kernel_launch(void* const* d_in, const int* in_sizes, int n_in,
                              void* d_out, int out_size, void* d_ws, size_t ws_size,
                              hipStream_t stream) {
    const float* x    = (const float*)d_in[0];
    const float* hs   = (const float*)d_in[1];
    const float* Wih0 = (const float*)d_in[2];
    const float* Whh0 = (const float*)d_in[3];
    const float* bih0 = (const float*)d_in[4];
    const float* bhh0 = (const float*)d_in[5];
    const float* Wih1 = (const float*)d_in[6];
    const float* Whh1 = (const float*)d_in[7];
    const float* bih1 = (const float*)d_in[8];
    const float* bhh1 = (const float*)d_in[9];
    const float* Wout = (const float*)d_in[10];
    const float* bout = (const float*)d_in[11];
    float* out = (float*)d_out;

    dim3 grid(BB / 4), block(128);
    hipLaunchKernelGGL(rnn_kernel, grid, block, 0, stream,
        x, hs, Wih0, Whh0, bih0, bhh0, Wih1, Whh1, bih1, bhh1, Wout, bout, out);
}

// Round 15
// 339.269 us; speedup vs baseline: 1.5714x; 1.3065x over previous
//
#include <hip/hip_runtime.h>

#define HID 10
#define TT  2048
#define BB  4096

typedef float f2 __attribute__((ext_vector_type(2)));

static __device__ __forceinline__ f2 pkmul(f2 a, f2 b) {
    f2 d; asm("v_pk_mul_f32 %0, %1, %2" : "=v"(d) : "v"(a), "v"(b)); return d;
}
static __device__ __forceinline__ f2 pkfma(f2 a, f2 b, f2 c) {
    f2 d; asm("v_pk_fma_f32 %0, %1, %2, %3" : "=v"(d) : "v"(a), "v"(b), "v"(c)); return d;
}

__device__ __forceinline__ float fast_tanh(float x) {
    // tanh(x) = 1 - 2/(exp2(x*2*log2e) + 1); saturates correctly at +-inf
    float e = exp2f(x * 2.885390081777926814f);
    float r = __builtin_amdgcn_rcpf(e + 1.0f);
    return fmaf(-2.0f, r, 1.0f);
}

// f32 -> bf16 bits, round-to-nearest-even (tanh output: no NaN/Inf concerns)
__device__ __forceinline__ unsigned short f2bf(float f) {
    unsigned u = __float_as_uint(f);
    return (unsigned short)((u + 0x7fffu + ((u >> 16) & 1u)) >> 16);
}
// unpack bf16x2 dword -> f2 {low, high}
__device__ __forceinline__ f2 unpk(unsigned d) {
    f2 r;
    r.x = __uint_as_float(d << 16);
    r.y = __uint_as_float(d & 0xffff0000u);
    return r;
}

// 2-wave specialization, DS-instruction-minimized (R8/R11 were DS-pipe-bound:
// 13 DS ops/block-step ~ 400 cyc/CU-step saturated the per-CU DS pipe):
//   wave A: h0 recurrence (bf16 LDS self-broadcast: b16 write + 2 reads) and
//           computes u(t) = Wih1.h0(t)+b1 from the broadcast it already holds,
//           publishing ONE f32 scalar to the u-ring. Lane10: u := b_out.
//   wave B: h1 recurrence (same bf16 broadcast scheme) reading only scalar u
//           (lag-1 epoch). Lane 10 rides Wout on the Whh1 dot -> s1 = out(t-1),
//           stored with the proven 1-step-lag quad carry.
// DS = 8 ops/block-step (was 13); broadcasts bf16 (absmax budget 1.74e-2).
__global__ void __launch_bounds__(128) rnn_kernel(
    const float* __restrict__ x,    const float* __restrict__ hs,
    const float* __restrict__ Wih0, const float* __restrict__ Whh0,
    const float* __restrict__ bih0, const float* __restrict__ bhh0,
    const float* __restrict__ Wih1, const float* __restrict__ Whh1,
    const float* __restrict__ bih1, const float* __restrict__ bhh1,
    const float* __restrict__ Wout, const float* __restrict__ boutp,
    float* __restrict__ out)
{
    const int tid   = threadIdx.x;
    const bool isA  = tid < 64;
    const int lane  = tid & 15;          // hidden unit slot
    const int grp   = (tid >> 4) & 3;    // row within block
    const int row   = blockIdx.x * 4 + grp;
    const bool act  = (lane < HID);
    const bool olane = (lane == HID);

    // per group, 272 floats (stride == 16 mod 32 banks -> <=2-way, free):
    //   [0..255]   u-ring [16 slots][16 lanes] f32
    //   [256..263] h0 broadcast buf: 16 ushort (bf16)
    //   [264..271] h1 broadcast buf: 16 ushort (bf16)
    __shared__ float lds[4 * 272];
    float* base = &lds[grp * 272];
    float* ur = base;
    unsigned short* h0b = (unsigned short*)(base + 256);
    unsigned short* h1b = (unsigned short*)(base + 264);

    const float* xrow = x   + (size_t)row * TT;
    float*       orow = out + (size_t)row * TT;

    // ---- role state ----
    f2 whh0p[5], wih1p[5];  float wih0i = 0.f, b0c = 0.f, ub = 0.f;  // A
    f2 whh1p[5];            float obias = 0.f;                        // B
    f2 H0[5], H1[5];
    float hown = 0.f;
    float4 xa = make_float4(0,0,0,0), xb = make_float4(0,0,0,0);
    float P1 = 0.f, P2 = 0.f, P3 = 0.f;

    if (isA) {
        #pragma unroll
        for (int j = 0; j < 5; ++j) {
            whh0p[j] = act ? f2{Whh0[lane*HID + 2*j], Whh0[lane*HID + 2*j+1]}
                           : f2{0.f, 0.f};
            wih1p[j] = act ? f2{Wih1[lane*HID + 2*j], Wih1[lane*HID + 2*j+1]}
                           : f2{0.f, 0.f};
        }
        wih0i = act ? Wih0[lane] : 0.f;
        b0c   = act ? (bih0[lane] + bhh0[lane]) : 0.f;
        ub    = act ? (bih1[lane] + bhh1[lane]) : (olane ? boutp[0] : 0.f);
        #pragma unroll
        for (int j = 0; j < 5; ++j)
            H0[j] = f2{hs[row*HID + 2*j], hs[row*HID + 2*j+1]};
        hown = act ? hs[row*HID + lane] : 0.f;
        xa = *(const float4*)(xrow);
        xb = *(const float4*)(xrow + 4);
    } else {
        #pragma unroll
        for (int j = 0; j < 5; ++j)
            whh1p[j] = act ? f2{Whh1[lane*HID + 2*j], Whh1[lane*HID + 2*j+1]}
                     : (olane ? f2{Wout[2*j], Wout[2*j+1]} : f2{0.f, 0.f});
        obias = olane ? boutp[0] : 0.f;
        #pragma unroll
        for (int j = 0; j < 5; ++j)
            H1[j] = f2{hs[BB*HID + row*HID + 2*j], hs[BB*HID + row*HID + 2*j+1]};
        hown = act ? hs[BB*HID + row*HID + lane] : 0.f;
    }

    const int M = TT / 8;   // 256 epochs of 8 steps
    for (int m = 0; m <= M; ++m) {
        if (isA) {
            if (m < M) {
                const int mn = (m + 1 < M) ? m + 1 : M - 1;
                const float4 xn0 = *(const float4*)(xrow + 8 * mn);
                const float4 xn1 = *(const float4*)(xrow + 8 * mn + 4);
                const float xs[8] = {xa.x, xa.y, xa.z, xa.w,
                                     xb.x, xb.y, xb.z, xb.w};
                #pragma unroll
                for (int k = 0; k < 8; ++k) {
                    // h0(t) = tanh(x*wih0 + Whh0 . h0(t-1) + b0)
                    f2 acc = pkmul(whh0p[0], H0[0]);
                    acc = pkfma(whh0p[1], H0[1], acc);
                    acc = pkfma(whh0p[2], H0[2], acc);
                    acc = pkfma(whh0p[3], H0[3], acc);
                    acc = pkfma(whh0p[4], H0[4], acc);
                    const float a0 = fmaf(xs[k], wih0i, b0c);
                    hown = fast_tanh((a0 + acc.x) + acc.y);
                    // bf16 self-broadcast: b16 write + b128/b32 readback
                    h0b[lane] = f2bf(hown);
                    __builtin_amdgcn_wave_barrier();
                    const uint4    rb = *(const uint4*)h0b;       // units 0..7
                    const unsigned rc = *(const unsigned*)(h0b+8); // units 8,9
                    __builtin_amdgcn_wave_barrier();
                    H0[0] = unpk(rb.x); H0[1] = unpk(rb.y);
                    H0[2] = unpk(rb.z); H0[3] = unpk(rb.w);
                    H0[4] = unpk(rc);
                    // u(t) = Wih1 . h0(t) + b1  (lane10: bout) -> publish
                    f2 uc = pkmul(wih1p[0], H0[0]);
                    uc = pkfma(wih1p[1], H0[1], uc);
                    uc = pkfma(wih1p[2], H0[2], uc);
                    uc = pkfma(wih1p[3], H0[3], uc);
                    uc = pkfma(wih1p[4], H0[4], uc);
                    ur[((8 * m + k) & 15) * 16 + lane] = (ub + uc.x) + uc.y;
                }
                xa = xn0; xb = xn1;
            }
        } else {
            if (m >= 1) {
                const int tb = 8 * (m - 1);
                float u[8];
                #pragma unroll
                for (int k = 0; k < 8; ++k)
                    u[k] = ur[((tb + k) & 15) * 16 + lane];
                float c[8];
                #pragma unroll
                for (int k = 0; k < 8; ++k) {
                    // s1(t) = u(t) + Whh1 . h1(t-1)   (rider: out(t-1))
                    f2 acc = pkmul(whh1p[0], H1[0]);
                    acc = pkfma(whh1p[1], H1[1], acc);
                    acc = pkfma(whh1p[2], H1[2], acc);
                    acc = pkfma(whh1p[3], H1[3], acc);
                    acc = pkfma(whh1p[4], H1[4], acc);
                    const float s1 = (u[k] + acc.x) + acc.y;
                    c[k] = s1;
                    hown = fast_tanh(s1);
                    h1b[lane] = f2bf(hown);
                    __builtin_amdgcn_wave_barrier();
                    const uint4    qb = *(const uint4*)h1b;
                    const unsigned qc = *(const unsigned*)(h1b+8);
                    __builtin_amdgcn_wave_barrier();
                    H1[0] = unpk(qb.x); H1[1] = unpk(qb.y);
                    H1[2] = unpk(qb.z); H1[3] = unpk(qb.w);
                    H1[4] = unpk(qc);
                }
                // c[k] = out(tb+k-1): aligned quads, 1-step lag
                if (olane) {
                    if (m >= 2)
                        *(float4*)(orow + tb - 4) = make_float4(P1, P2, P3, c[0]);
                    *(float4*)(orow + tb) = make_float4(c[1], c[2], c[3], c[4]);
                }
                P1 = c[5]; P2 = c[6]; P3 = c[7];
            }
        }
        __syncthreads();
    }

    if (!isA) {
        // epilogue: out(2047) = bout + Wout . h1(2047) via rider weights
        f2 e = pkmul(whh1p[0], H1[0]);
        e = pkfma(whh1p[1], H1[1], e);
        e = pkfma(whh1p[2], H1[2], e);
        e = pkfma(whh1p[3], H1[3], e);
        e = pkfma(whh1p[4], H1[4], e);
        if (olane)
            *(float4*)(orow + TT - 4) = make_float4(P1, P2, P3, (obias + e.x) + e.y);
        if (act)
            out[(size_t)BB*TT + (size_t)BB*HID + (size_t)row*HID + lane] = hown;
    } else {
        if (act)
            out[(size_t)BB*TT + (size_t)row*HID + lane] = hown;
    }
}

extern "C" void kernel_launch(void* const* d_in, const int* in_sizes, int n_in,
                              void* d_out, int out_size, void* d_ws, size_t ws_size,
                              hipStream_t stream) {
    const float* x    = (const float*)d_in[0];
    const float* hs   = (const float*)d_in[1];
    const float* Wih0 = (const float*)d_in[2];
    const float* Whh0 = (const float*)d_in[3];
    const float* bih0 = (const float*)d_in[4];
    const float* bhh0 = (const float*)d_in[5];
    const float* Wih1 = (const float*)d_in[6];
    const float* Whh1 = (const float*)d_in[7];
    const float* bih1 = (const float*)d_in[8];
    const float* bhh1 = (const float*)d_in[9];
    const float* Wout = (const float*)d_in[10];
    const float* bout = (const float*)d_in[11];
    float* out = (float*)d_out;

    dim3 grid(BB / 4), block(128);
    hipLaunchKernelGGL(rnn_kernel, grid, block, 0, stream,
        x, hs, Wih0, Whh0, bih0, bhh0, Wih1, Whh1, bih1, bhh1, Wout, bout, out);
}

// Round 16
// 328.600 us; speedup vs baseline: 1.6224x; 1.0325x over previous
//
#include <hip/hip_runtime.h>

#define HID 10
#define TT  2048
#define BB  4096

typedef float f2 __attribute__((ext_vector_type(2)));

static __device__ __forceinline__ f2 pkmul(f2 a, f2 b) {
    f2 d; asm("v_pk_mul_f32 %0, %1, %2" : "=v"(d) : "v"(a), "v"(b)); return d;
}
static __device__ __forceinline__ f2 pkfma(f2 a, f2 b, f2 c) {
    f2 d; asm("v_pk_fma_f32 %0, %1, %2, %3" : "=v"(d) : "v"(a), "v"(b), "v"(c)); return d;
}

__device__ __forceinline__ float fast_tanh(float x) {
    // tanh(x) = 1 - 2/(exp2(x*2*log2e) + 1); saturates correctly at +-inf
    float e = exp2f(x * 2.885390081777926814f);
    float r = __builtin_amdgcn_rcpf(e + 1.0f);
    return fmaf(-2.0f, r, 1.0f);
}

// INTRA-WAVE pipeline, ZERO __syncthreads. One wave = full 2-layer pipeline
// for 2 rows. Lane groups (16 lanes each): [rowsub][role]:
//   role 0 (L0): h0(i) = tanh(x(i)w + Whh0.h0(i-1) + b0), then u(i) =
//                Wih1.h0(i)+b1 from its own readback; publishes scalar u
//                to a 2-slot ring. Lane10-L0 publishes u := b_out.
//   role 1 (L1): lag-2: h1(i-2) = tanh(u(i-2) + Whh1.h1(i-3)); u read one
//                step early (full-step latency cover). Lane10-L1 rides Wout
//                -> its pre-tanh sum = out(i-3), stored as aligned quads.
// Same-wave DS program order makes the u handoff race-free: no barriers,
// 2048 independent 1-wave blocks = 2 waves/SIMD, chains overlap freely
// (R8/R11's __syncthreads convoyed waves -> aligned stalls -> 344 cyc/step).
__global__ void __launch_bounds__(64) rnn_kernel(
    const float* __restrict__ x,    const float* __restrict__ hs,
    const float* __restrict__ Wih0, const float* __restrict__ Whh0,
    const float* __restrict__ bih0, const float* __restrict__ bhh0,
    const float* __restrict__ Wih1, const float* __restrict__ Whh1,
    const float* __restrict__ bih1, const float* __restrict__ bhh1,
    const float* __restrict__ Wout, const float* __restrict__ boutp,
    float* __restrict__ out)
{
    const int tid  = threadIdx.x;
    const int lane = tid & 15;          // hidden unit slot
    const int ro   = (tid >> 4) & 1;    // 0 = layer-0 role, 1 = layer-1 role
    const int rs   = tid >> 5;          // row within pair
    const int row  = blockIdx.x * 2 + rs;
    const bool act = (lane < HID);
    const bool ol  = (lane == HID);

    // per row (stride 104 floats -> row1 regions phase-shifted by 8 banks):
    //   [0:16) h0 buf | [16:32) h1 buf | [32:64) u ring (2 slots) |
    //   [64:96) trash (2 slots, role-1's dummy u-writes)
    // all simultaneous 4-group accesses land in distinct/2-way bank phases.
    __shared__ float lds[2 * 104];
    const int Br = rs * 104;
    float*       hws = &lds[Br + ro * 16 + lane];     // own h write slot
    const float* hrb = &lds[Br + ro * 16];            // own h read base
    float*       uws = &lds[Br + (ro ? 64 : 32) + lane]; // u write (L1->trash)
    const float* urs = &lds[Br + (ro ? 32 : 64) + lane]; // u read  (L0->trash)

    // ---- role-selected weights / seeds ----
    f2 W1[5], W2[5];
    float wsel, bsd, d2s;
    f2 H[5];
    if (ro == 0) {
        #pragma unroll
        for (int j = 0; j < 5; ++j) {
            W1[j] = act ? f2{Whh0[lane*HID + 2*j], Whh0[lane*HID + 2*j+1]}
                        : f2{0.f, 0.f};
            W2[j] = act ? f2{Wih1[lane*HID + 2*j], Wih1[lane*HID + 2*j+1]}
                        : f2{0.f, 0.f};
            H[j]  = f2{hs[row*HID + 2*j], hs[row*HID + 2*j+1]};
        }
        wsel = act ? Wih0[lane] : 0.f;
        bsd  = act ? (bih0[lane] + bhh0[lane]) : 0.f;
        d2s  = act ? (bih1[lane] + bhh1[lane]) : (ol ? boutp[0] : 0.f);
    } else {
        #pragma unroll
        for (int j = 0; j < 5; ++j) {
            W1[j] = act ? f2{Whh1[lane*HID + 2*j], Whh1[lane*HID + 2*j+1]}
                  : (ol ? f2{Wout[2*j], Wout[2*j+1]} : f2{0.f, 0.f});
            W2[j] = f2{0.f, 0.f};
            H[j]  = f2{hs[BB*HID + row*HID + 2*j], hs[BB*HID + row*HID + 2*j+1]};
        }
        wsel = 1.f; bsd = 0.f; d2s = 0.f;
    }

    const float* xrow = x   + (size_t)row * TT;
    float*       orow = out + (size_t)row * TT;

    float4 xa = *(const float4*)(xrow);
    float4 xb = *(const float4*)(xrow + 4);

    float uprev = 0.f, hcur = 0.f;
    float cap[8], P = 0.f;

// One pipeline step. S = i&1 (compile-time). MASKP: prologue (role-1 state
// frozen). CV receives pre-tanh sum (lane10-role1: out(i-3)).
#define STEP(XK, S, CV, MASKP)                                          \
  do {                                                                  \
    const float xin = ro ? uprev : (XK);                                \
    float s_ = fmaf(xin, wsel, bsd);                                    \
    f2 ac = pkmul(W1[0], H[0]);                                         \
    ac = pkfma(W1[1], H[1], ac);                                        \
    ac = pkfma(W1[2], H[2], ac);                                        \
    ac = pkfma(W1[3], H[3], ac);                                        \
    ac = pkfma(W1[4], H[4], ac);                                        \
    const float s1_ = (s_ + ac.x) + ac.y;                               \
    CV = s1_;                                                           \
    hcur = fast_tanh(s1_);                                              \
    if (!(MASKP) || ro == 0) *hws = hcur;                               \
    __builtin_amdgcn_wave_barrier();                                    \
    {                                                                   \
      const float4 r0_ = *(const float4*)(hrb);                         \
      const float4 r1_ = *(const float4*)(hrb + 4);                     \
      const f2     r2_ = *(const f2*)(hrb + 8);                         \
      if (!(MASKP) || ro == 0) {                                        \
        H[0] = f2{r0_.x, r0_.y}; H[1] = f2{r0_.z, r0_.w};               \
        H[2] = f2{r1_.x, r1_.y}; H[3] = f2{r1_.z, r1_.w};               \
        H[4] = r2_;                                                     \
      }                                                                 \
    }                                                                   \
    f2 a2 = pkmul(W2[0], H[0]);                                         \
    a2 = pkfma(W2[1], H[1], a2);                                        \
    a2 = pkfma(W2[2], H[2], a2);                                        \
    a2 = pkfma(W2[3], H[3], a2);                                        \
    a2 = pkfma(W2[4], H[4], a2);                                        \
    uws[(S) * 16] = (d2s + a2.x) + a2.y;                                \
    __builtin_amdgcn_wave_barrier();                                    \
    uprev = urs[((S) ^ 1) * 16];                                        \
  } while (0)

    // -------- epoch 0 (i = 0..7): steps 0,1 prologue-masked --------
    {
        const float4 xn0 = *(const float4*)(xrow + 8);
        const float4 xn1 = *(const float4*)(xrow + 12);
        float dm;
        STEP(xa.x, 0, dm, true);
        STEP(xa.y, 1, dm, true);
        STEP(xa.z, 0, cap[2], false);
        STEP(xa.w, 1, cap[3], false);
        STEP(xb.x, 0, cap[4], false);
        STEP(xb.y, 1, cap[5], false);
        STEP(xb.z, 0, cap[6], false);
        STEP(xb.w, 1, cap[7], false);
        // cap[k] = out(k-3): out(0..3) = cap[3..6]
        if (ro && ol)
            *(float4*)(orow) = make_float4(cap[3], cap[4], cap[5], cap[6]);
        P = cap[7];                       // out(4)
        xa = xn0; xb = xn1;
    }

    // -------- main epochs m = 1..255 (i = 8m..8m+7) --------
    for (int m = 1; m < TT / 8; ++m) {
        const int mn = (m + 1 < TT / 8) ? m + 1 : TT / 8 - 1;
        const float4 xn0 = *(const float4*)(xrow + 8 * mn);
        const float4 xn1 = *(const float4*)(xrow + 8 * mn + 4);
        STEP(xa.x, 0, cap[0], false);
        STEP(xa.y, 1, cap[1], false);
        STEP(xa.z, 0, cap[2], false);
        STEP(xa.w, 1, cap[3], false);
        if (ro && ol)   // out(8m-4..8m-1)
            *(float4*)(orow + 8*m - 4) = make_float4(P, cap[0], cap[1], cap[2]);
        STEP(xb.x, 0, cap[4], false);
        STEP(xb.y, 1, cap[5], false);
        STEP(xb.z, 0, cap[6], false);
        STEP(xb.w, 1, cap[7], false);
        if (ro && ol)   // out(8m..8m+3)
            *(float4*)(orow + 8*m) = make_float4(cap[3], cap[4], cap[5], cap[6]);
        P = cap[7];
        xa = xn0; xb = xn1;
    }

    // -------- epilogue: drain role-1 (steps 2048..2050, x unused) --------
    const float h0fin = hcur;             // role-0 lanes: h0(2047)
    float e1, e2, e3;
    STEP(0.f, 0, e1, false);              // cap = out(2045)
    STEP(0.f, 1, e2, false);              // cap = out(2046); h1(2047) computed
    const float h1fin = hcur;             // role-1 lanes: h1(2047)
    STEP(0.f, 0, e3, false);              // rider cap = out(2047)
    if (ro && ol)
        *(float4*)(orow + TT - 4) = make_float4(P, e1, e2, e3);

    // final hidden state: [2, B, H] appended after B*T outputs
    if (!ro && act)
        out[(size_t)BB*TT + (size_t)row*HID + lane] = h0fin;
    if (ro && act)
        out[(size_t)BB*TT + (size_t)BB*HID + (size_t)row*HID + lane] = h1fin;

#undef STEP
}

extern "C" void kernel_launch(void* const* d_in, const int* in_sizes, int n_in,
                              void* d_out, int out_size, void* d_ws, size_t ws_size,
                              hipStream_t stream) {
    const float* x    = (const float*)d_in[0];
    const float* hs   = (const float*)d_in[1];
    const float* Wih0 = (const float*)d_in[2];
    const float* Whh0 = (const float*)d_in[3];
    const float* bih0 = (const float*)d_in[4];
    const float* bhh0 = (const float*)d_in[5];
    const float* Wih1 = (const float*)d_in[6];
    const float* Whh1 = (const float*)d_in[7];
    const float* bih1 = (const float*)d_in[8];
    const float* bhh1 = (const float*)d_in[9];
    const float* Wout = (const float*)d_in[10];
    const float* bout = (const float*)d_in[11];
    float* out = (float*)d_out;

    dim3 grid(BB / 2), block(64);
    hipLaunchKernelGGL(rnn_kernel, grid, block, 0, stream,
        x, hs, Wih0, Whh0, bih0, bhh0, Wih1, Whh1, bih1, bhh1, Wout, bout, out);
}

// Round 17
// 317.656 us; speedup vs baseline: 1.6783x; 1.0345x over previous
//
#include <hip/hip_runtime.h>

#define HID 10
#define TT  2048
#define BB  4096

typedef float f2 __attribute__((ext_vector_type(2)));

static __device__ __forceinline__ f2 pkmul(f2 a, f2 b) {
    f2 d; asm("v_pk_mul_f32 %0, %1, %2" : "=v"(d) : "v"(a), "v"(b)); return d;
}
static __device__ __forceinline__ f2 pkfma(f2 a, f2 b, f2 c) {
    f2 d; asm("v_pk_fma_f32 %0, %1, %2, %3" : "=v"(d) : "v"(a), "v"(b), "v"(c)); return d;
}

__device__ __forceinline__ float fast_tanh(float x) {
    // tanh(x) = 1 - 2/(exp2(x*2*log2e) + 1); saturates correctly at +-inf
    float e = exp2f(x * 2.885390081777926814f);
    float r = __builtin_amdgcn_rcpf(e + 1.0f);
    return fmaf(-2.0f, r, 1.0f);
}

// R16 intra-wave pipeline with the three measured stalls removed:
//  - u read TWO steps early (end of step i -> consumed step i+2): the LDS
//    read latency hides under one full step. Single u slot; same-wave DS
//    program order makes it race-free. (R16 consumed it 0 insts after read.)
//  - h readback issued IMMEDIATELY after the h write; the u-dot uses the
//    OLD H (publishes u(i-1) = Wih1.h0(i-1)+b1) so nothing blocks on the
//    fresh read until the next step's W1 dot.
//  - bank-conflict-free phases (R16 had 1.68e7 conflicts): row stride 72,
//    regions +0/+16/+32/+48 -> all simultaneous group accesses <=2-way.
// Pipeline: L0@i computes h0(i), publishes u(i-1); L1@j computes h1(j-3);
// rider lane10-L1 (W1=Wout, its u = b_out) captures out(j-4). No barriers.
__global__ void __launch_bounds__(64) rnn_kernel(
    const float* __restrict__ x,    const float* __restrict__ hs,
    const float* __restrict__ Wih0, const float* __restrict__ Whh0,
    const float* __restrict__ bih0, const float* __restrict__ bhh0,
    const float* __restrict__ Wih1, const float* __restrict__ Whh1,
    const float* __restrict__ bih1, const float* __restrict__ bhh1,
    const float* __restrict__ Wout, const float* __restrict__ boutp,
    float* __restrict__ out)
{
    const int tid  = threadIdx.x;
    const int lane = tid & 15;          // hidden unit slot
    const int ro   = (tid >> 4) & 1;    // 0 = layer-0 role, 1 = layer-1 role
    const int rs   = tid >> 5;          // row within pair
    const int row  = blockIdx.x * 2 + rs;
    const bool act = (lane < HID);
    const bool ol  = (lane == HID);

    // per row (stride 72 => row1 phase-shifted 8 banks):
    //   h0 buf @0, h1 buf @16, u-real @32 (L0 writes, L1 reads),
    //   u-trash @48 (L1 writes, L0 reads). All 4-group accesses <=2-way;
    //   broadcast b128 readbacks land on disjoint bank quads.
    __shared__ float lds[2 * 72];
    const int Br = rs * 72;
    float*       hws = &lds[Br + ro * 16 + lane];
    const float* hrb = &lds[Br + ro * 16];
    float*       uws = &lds[Br + (ro ? 48 : 32) + lane];
    const float* urs = &lds[Br + (ro ? 32 : 48) + lane];

    // ---- role-selected weights / seeds ----
    f2 W1[5], W2[5], H[5];
    float wsel, bsd, d2s;
    if (ro == 0) {
        #pragma unroll
        for (int j = 0; j < 5; ++j) {
            W1[j] = act ? f2{Whh0[lane*HID + 2*j], Whh0[lane*HID + 2*j+1]}
                        : f2{0.f, 0.f};
            W2[j] = act ? f2{Wih1[lane*HID + 2*j], Wih1[lane*HID + 2*j+1]}
                        : f2{0.f, 0.f};
            H[j]  = f2{hs[row*HID + 2*j], hs[row*HID + 2*j+1]};
        }
        wsel = act ? Wih0[lane] : 0.f;
        bsd  = act ? (bih0[lane] + bhh0[lane]) : 0.f;
        d2s  = act ? (bih1[lane] + bhh1[lane]) : (ol ? boutp[0] : 0.f);
    } else {
        #pragma unroll
        for (int j = 0; j < 5; ++j) {
            W1[j] = act ? f2{Whh1[lane*HID + 2*j], Whh1[lane*HID + 2*j+1]}
                  : (ol ? f2{Wout[2*j], Wout[2*j+1]} : f2{0.f, 0.f});
            W2[j] = f2{0.f, 0.f};
            H[j]  = f2{hs[BB*HID + row*HID + 2*j], hs[BB*HID + row*HID + 2*j+1]};
        }
        wsel = 1.f; bsd = 0.f; d2s = 0.f;
    }

    const float* xrow = x   + (size_t)row * TT;
    float*       orow = out + (size_t)row * TT;

    float hcur = act ? (ro ? hs[BB*HID + row*HID + lane] : hs[row*HID + lane]) : 0.f;
    float ucur = 0.f, u1 = 0.f;
    float cap[8];

// One pipeline step. CV captures pre-tanh sum (lane10-role1: out(i-4)).
// MASKP freezes role-1 state during the 3 prologue steps.
#define STEP(XK, CV, MASKP) do {                                        \
    const float xin = ro ? ucur : (XK);                                 \
    float s_ = fmaf(xin, wsel, bsd);                                    \
    f2 ac = pkmul(W1[0], H[0]);                                         \
    ac = pkfma(W1[1], H[1], ac);                                        \
    ac = pkfma(W1[2], H[2], ac);                                        \
    ac = pkfma(W1[3], H[3], ac);                                        \
    ac = pkfma(W1[4], H[4], ac);                                        \
    const float s1_ = (s_ + ac.x) + ac.y;                               \
    CV = s1_;                                                           \
    const float hn_ = fast_tanh(s1_);                                   \
    if (!(MASKP) || ro == 0) { hcur = hn_; *hws = hcur; }               \
    __builtin_amdgcn_wave_barrier();                                    \
    const float4 r0_ = *(const float4*)(hrb);     /* issued early */    \
    const float4 r1_ = *(const float4*)(hrb + 4);                       \
    const f2     r2_ = *(const f2*)(hrb + 8);                           \
    f2 a2 = pkmul(W2[0], H[0]);                   /* u from OLD H */    \
    a2 = pkfma(W2[1], H[1], a2);                                        \
    a2 = pkfma(W2[2], H[2], a2);                                        \
    a2 = pkfma(W2[3], H[3], a2);                                        \
    a2 = pkfma(W2[4], H[4], a2);                                        \
    *uws = (d2s + a2.x) + a2.y;                                         \
    __builtin_amdgcn_wave_barrier();                                    \
    ucur = u1;                                                          \
    u1 = *urs;                                    /* for step i+2 */    \
    if (!(MASKP) || ro == 0) {                                          \
      H[0] = f2{r0_.x, r0_.y}; H[1] = f2{r0_.z, r0_.w};                 \
      H[2] = f2{r1_.x, r1_.y}; H[3] = f2{r1_.z, r1_.w};                 \
      H[4] = r2_;                                                       \
    }                                                                   \
} while (0)

    float4 xa = *(const float4*)(xrow);
    float4 xb = *(const float4*)(xrow + 4);

    // -------- epoch 0 (steps 0..7): first 3 steps role-1-masked --------
    {
        const float4 xn0 = *(const float4*)(xrow + 8);
        const float4 xn1 = *(const float4*)(xrow + 12);
        STEP(xa.x, cap[0], true);
        STEP(xa.y, cap[1], true);
        STEP(xa.z, cap[2], true);
        STEP(xa.w, cap[3], false);
        STEP(xb.x, cap[4], false);   // out(0)
        STEP(xb.y, cap[5], false);
        STEP(xb.z, cap[6], false);
        STEP(xb.w, cap[7], false);   // out(3)
        if (ro && ol)
            *(float4*)(orow) = make_float4(cap[4], cap[5], cap[6], cap[7]);
        xa = xn0; xb = xn1;
    }

    // -------- main epochs m = 1..255 (steps 8m..8m+7) --------
    for (int m = 1; m < TT / 8; ++m) {
        const int mn = (m + 1 < TT / 8) ? m + 1 : TT / 8 - 1;
        const float4 xn0 = *(const float4*)(xrow + 8 * mn);
        const float4 xn1 = *(const float4*)(xrow + 8 * mn + 4);
        STEP(xa.x, cap[0], false);   // out(8m-4)
        STEP(xa.y, cap[1], false);
        STEP(xa.z, cap[2], false);
        STEP(xa.w, cap[3], false);   // out(8m-1)
        if (ro && ol)
            *(float4*)(orow + 8*m - 4) = make_float4(cap[0], cap[1], cap[2], cap[3]);
        STEP(xb.x, cap[4], false);   // out(8m)
        STEP(xb.y, cap[5], false);
        STEP(xb.z, cap[6], false);
        STEP(xb.w, cap[7], false);   // out(8m+3)
        if (ro && ol)
            *(float4*)(orow + 8*m) = make_float4(cap[4], cap[5], cap[6], cap[7]);
        xa = xn0; xb = xn1;
    }

    // -------- drain: steps 2048..2051, captures out(2044..2047) --------
    const float h0fin = hcur;            // role-0 lanes: h0(2047)
    float e0, e1, e2, e3;
    STEP(0.f, e0, false);                // out(2044)
    STEP(0.f, e1, false);                // out(2045)
    STEP(0.f, e2, false);                // out(2046); h1(2047) computed here
    const float h1fin = hcur;            // role-1 lanes: h1(2047)
    STEP(0.f, e3, false);                // out(2047)
    if (ro && ol)
        *(float4*)(orow + TT - 4) = make_float4(e0, e1, e2, e3);

    // final hidden state: [2, B, H] appended after B*T outputs
    if (!ro && act)
        out[(size_t)BB*TT + (size_t)row*HID + lane] = h0fin;
    if (ro && act)
        out[(size_t)BB*TT + (size_t)BB*HID + (size_t)row*HID + lane] = h1fin;

#undef STEP
}

extern "C" void kernel_launch(void* const* d_in, const int* in_sizes, int n_in,
                              void* d_out, int out_size, void* d_ws, size_t ws_size,
                              hipStream_t stream) {
    const float* x    = (const float*)d_in[0];
    const float* hs   = (const float*)d_in[1];
    const float* Wih0 = (const float*)d_in[2];
    const float* Whh0 = (const float*)d_in[3];
    const float* bih0 = (const float*)d_in[4];
    const float* bhh0 = (const float*)d_in[5];
    const float* Wih1 = (const float*)d_in[6];
    const float* Whh1 = (const float*)d_in[7];
    const float* bih1 = (const float*)d_in[8];
    const float* bhh1 = (const float*)d_in[9];
    const float* Wout = (const float*)d_in[10];
    const float* bout = (const float*)d_in[11];
    float* out = (float*)d_out;

    dim3 grid(BB / 2), block(64);
    hipLaunchKernelGGL(rnn_kernel, grid, block, 0, stream,
        x, hs, Wih0, Whh0, bih0, bhh0, Wih1, Whh1, bih1, bhh1, Wout, bout, out);
}

// Round 18
// 277.354 us; speedup vs baseline: 1.9222x; 1.1453x over previous
//
#include <hip/hip_runtime.h>

#define HID 10
#define TT  2048
#define BB  4096

typedef float f2 __attribute__((ext_vector_type(2)));

static __device__ __forceinline__ f2 pkmul(f2 a, f2 b) {
    f2 d; asm("v_pk_mul_f32 %0, %1, %2" : "=v"(d) : "v"(a), "v"(b)); return d;
}
static __device__ __forceinline__ f2 pkfma(f2 a, f2 b, f2 c) {
    f2 d; asm("v_pk_fma_f32 %0, %1, %2, %3" : "=v"(d) : "v"(a), "v"(b), "v"(c)); return d;
}

__device__ __forceinline__ float fast_tanh(float x) {
    // tanh(x) = 1 - 2/(exp2(x*2*log2e) + 1); saturates correctly at +-inf
    float e = exp2f(x * 2.885390081777926814f);
    float r = __builtin_amdgcn_rcpf(e + 1.0f);
    return fmaf(-2.0f, r, 1.0f);
}

#define PKDOT(ACC, W, H)                 \
    ACC = pkmul(W[0], H[0]);             \
    ACC = pkfma(W[1], H[1], ACC);        \
    ACC = pkfma(W[2], H[2], ACC);        \
    ACC = pkfma(W[3], H[3], ACC);        \
    ACC = pkfma(W[4], H[4], ACC);

// DS-pipe-minimized 2-wave specialization (17-round model: step time ==
// DS-pipe term; R11 = 13 DS-insts/block-step ~ 312 cyc/CU-step ~ 344 meas).
// This design: 10 DS/block-step.
//   wave A: h0 recurrence; u(i-1) = Wih1.h0(i-1)+b1 computed on the OLD H0
//           (doubles as h0-readback latency cover, R17 trick) and published
//           as ONE f32/lane into a 16-slot ring. Lane10 publishes b_out.
//           DS/step: h0 write + 3 readback + u write = 5.
//   wave B: h1 recurrence, lag ~8: epoch m processes j = 8m-9..8m-2 using
//           u's prefetched at epoch start. Lane10 rides Wout on the Whh1
//           dot -> s1 = out(j-1), stored via 2-value lag carry.
//           DS/step: h1 write + 3 readback = 4 (+1 amortized u prefetch).
// Barrier once per 8-step epoch (258 total). 2048 waves = 2/SIMD.
__global__ void __launch_bounds__(128) rnn_kernel(
    const float* __restrict__ x,    const float* __restrict__ hs,
    const float* __restrict__ Wih0, const float* __restrict__ Whh0,
    const float* __restrict__ bih0, const float* __restrict__ bhh0,
    const float* __restrict__ Wih1, const float* __restrict__ Whh1,
    const float* __restrict__ bih1, const float* __restrict__ bhh1,
    const float* __restrict__ Wout, const float* __restrict__ boutp,
    float* __restrict__ out)
{
    const int tid  = threadIdx.x;
    const bool isA = tid < 64;
    const int lane = tid & 15;           // hidden unit slot
    const int grp  = (tid >> 4) & 3;     // row within block
    const int row  = blockIdx.x * 4 + grp;
    const bool act = (lane < HID);
    const bool ol  = (lane == HID);      // rider lane

    // per row 296 floats (mod 32 = 8 -> rows at bank phases 0/8/16/24):
    //   u-ring [16 slots][16 lanes] @0, h0 buf @256 (phase+0),
    //   h1 buf @280 (phase+24). All instruction-level accesses <=2-way or
    //   broadcast (free).
    __shared__ float lds[4 * 296];
    float* base = &lds[grp * 296];
    float* up   = base + lane;           // u-ring lane pointer
    float* h0b  = base + 256;
    float* h1b  = base + 280;

    const float* xrow = x   + (size_t)row * TT;
    float*       orow = out + (size_t)row * TT;

    // ---- role state ----
    f2 W0[5], W1[5], W2[5], H0[5], H1[5];
    float wih0i = 0.f, b0c = 0.f, ub = 0.f, obias = 0.f;
    float hown = 0.f;
    float4 xa = make_float4(0,0,0,0), xb = make_float4(0,0,0,0);
    float P1 = 0.f, P2 = 0.f;

    if (isA) {
        #pragma unroll
        for (int j = 0; j < 5; ++j) {
            W0[j] = act ? f2{Whh0[lane*HID + 2*j], Whh0[lane*HID + 2*j+1]}
                        : f2{0.f, 0.f};
            W1[j] = act ? f2{Wih1[lane*HID + 2*j], Wih1[lane*HID + 2*j+1]}
                        : f2{0.f, 0.f};
            H0[j] = f2{hs[row*HID + 2*j], hs[row*HID + 2*j+1]};
        }
        wih0i = act ? Wih0[lane] : 0.f;
        b0c   = act ? (bih0[lane] + bhh0[lane]) : 0.f;
        ub    = act ? (bih1[lane] + bhh1[lane]) : (ol ? boutp[0] : 0.f);
        hown  = act ? hs[row*HID + lane] : 0.f;
        xa = *(const float4*)(xrow);
        xb = *(const float4*)(xrow + 4);
    } else {
        #pragma unroll
        for (int j = 0; j < 5; ++j) {
            W2[j] = act ? f2{Whh1[lane*HID + 2*j], Whh1[lane*HID + 2*j+1]}
                  : (ol ? f2{Wout[2*j], Wout[2*j+1]} : f2{0.f, 0.f});
            H1[j] = f2{hs[BB*HID + row*HID + 2*j], hs[BB*HID + row*HID + 2*j+1]};
        }
        obias = ol ? boutp[0] : 0.f;
    }

    // main loop: A epochs 0..255 (steps 8m..8m+7, publishes u(8m-1..8m+6));
    //            B epochs 1..256 (j = 8m-9..8m-2, all u's already published).
    for (int m = 0; m <= 256; ++m) {
        if (isA) {
            if (m <= 255) {
                const int mn = (m + 1 <= 255) ? m + 1 : 255;
                const float4 xn0 = *(const float4*)(xrow + 8 * mn);
                const float4 xn1 = *(const float4*)(xrow + 8 * mn + 4);
                const float xs[8] = {xa.x, xa.y, xa.z, xa.w,
                                     xb.x, xb.y, xb.z, xb.w};
                const int sb = (m & 1) * 8;
                #pragma unroll
                for (int k = 0; k < 8; ++k) {
                    // h0(i) = tanh(x(i)*wih0 + Whh0 . h0(i-1) + b0)
                    f2 ac; PKDOT(ac, W0, H0);
                    const float s0 = fmaf(xs[k], wih0i, b0c);
                    hown = fast_tanh((s0 + ac.x) + ac.y);
                    h0b[lane] = hown;
                    __builtin_amdgcn_wave_barrier();
                    const float4 r0 = *(const float4*)(h0b);      // issued early
                    const float4 r1 = *(const float4*)(h0b + 4);
                    const f2     r2 = *(const f2*)(h0b + 8);
                    // u(i-1) on OLD H0 (covers readback latency)
                    f2 uc; PKDOT(uc, W1, H0);
                    up[((sb + k + 15) & 15) * 16] = (ub + uc.x) + uc.y;
                    H0[0] = f2{r0.x, r0.y}; H0[1] = f2{r0.z, r0.w};
                    H0[2] = f2{r1.x, r1.y}; H0[3] = f2{r1.z, r1.w};
                    H0[4] = r2;
                }
                xa = xn0; xb = xn1;
            }
        } else {
            if (m >= 1) {
                const int bb = (m & 1) ? 15 : 7;   // first slot of this epoch
                float u[8];
                #pragma unroll
                for (int k = 0; k < 8; ++k)
                    u[k] = up[((bb + k) & 15) * 16];
                float c[8];
                #pragma unroll
                for (int k = 0; k < 8; ++k) {
                    // j = 8m-9+k; h1(j) = tanh(u(j) + Whh1 . h1(j-1))
                    f2 ac; PKDOT(ac, W2, H1);
                    const float s1 = (u[k] + ac.x) + ac.y;  // lane10: out(j-1)
                    c[k] = s1;
                    const float hn = fast_tanh(s1);
                    h1b[lane] = hn;
                    __builtin_amdgcn_wave_barrier();
                    const float4 q0 = *(const float4*)(h1b);
                    const float4 q1 = *(const float4*)(h1b + 4);
                    const f2     q2 = *(const f2*)(h1b + 8);
                    if (k > 0 || m > 1) {     // mask j = -1 (m=1, k=0)
                        H1[0] = f2{q0.x, q0.y}; H1[1] = f2{q0.z, q0.w};
                        H1[2] = f2{q1.x, q1.y}; H1[3] = f2{q1.z, q1.w};
                        H1[4] = q2;
                    }
                }
                // c[k] = out(8m-10+k); quads with 2-value carry
                if (ol) {
                    if (m == 1) {
                        *(float4*)(orow) = make_float4(c[2], c[3], c[4], c[5]);
                    } else {
                        *(float4*)(orow + 8*m - 12) = make_float4(P1, P2, c[0], c[1]);
                        *(float4*)(orow + 8*m - 8)  = make_float4(c[2], c[3], c[4], c[5]);
                    }
                }
                P1 = c[6]; P2 = c[7];
            }
        }
        __syncthreads();
    }

    // ---- tail: u(2047) publish by A, then B computes h1(2047) + out ----
    if (isA) {
        f2 uc; PKDOT(uc, W1, H0);                // H0 = h0(2047)
        up[15 * 16] = (ub + uc.x) + uc.y;        // slot 2047 & 15 = 15
    }
    __syncthreads();
    if (!isA) {
        const float u47 = up[15 * 16];
        f2 ac; PKDOT(ac, W2, H1);                // H1 = h1(2046)
        const float sA = (u47 + ac.x) + ac.y;    // lane10: out(2046)
        const float h1f = fast_tanh(sA);
        h1b[lane] = h1f;
        __builtin_amdgcn_wave_barrier();
        const float4 q0 = *(const float4*)(h1b);
        const float4 q1 = *(const float4*)(h1b + 4);
        const f2     q2 = *(const f2*)(h1b + 8);
        H1[0] = f2{q0.x, q0.y}; H1[1] = f2{q0.z, q0.w};
        H1[2] = f2{q1.x, q1.y}; H1[3] = f2{q1.z, q1.w};
        H1[4] = q2;                              // h1(2047)
        f2 a2; PKDOT(a2, W2, H1);
        const float o47 = (obias + a2.x) + a2.y; // lane10: out(2047)
        if (ol)
            *(float4*)(orow + TT - 4) = make_float4(P1, P2, sA, o47);
        if (act)
            out[(size_t)BB*TT + (size_t)BB*HID + (size_t)row*HID + lane] = h1f;
    } else {
        if (act)
            out[(size_t)BB*TT + (size_t)row*HID + lane] = hown;   // h0(2047)
    }
}

extern "C" void kernel_launch(void* const* d_in, const int* in_sizes, int n_in,
                              void* d_out, int out_size, void* d_ws, size_t ws_size,
                              hipStream_t stream) {
    const float* x    = (const float*)d_in[0];
    const float* hs   = (const float*)d_in[1];
    const float* Wih0 = (const float*)d_in[2];
    const float* Whh0 = (const float*)d_in[3];
    const float* bih0 = (const float*)d_in[4];
    const float* bhh0 = (const float*)d_in[5];
    const float* Wih1 = (const float*)d_in[6];
    const float* Whh1 = (const float*)d_in[7];
    const float* bih1 = (const float*)d_in[8];
    const float* bhh1 = (const float*)d_in[9];
    const float* Wout = (const float*)d_in[10];
    const float* bout = (const float*)d_in[11];
    float* out = (float*)d_out;

    dim3 grid(BB / 4), block(128);
    hipLaunchKernelGGL(rnn_kernel, grid, block, 0, stream,
        x, hs, Wih0, Whh0, bih0, bhh0, Wih1, Whh1, bih1, bhh1, Wout, bout, out);
}